// Round 3
// baseline (132.490 us; speedup 1.0000x reference)
//
#include <hip/hip_runtime.h>

// FeatureAlign, MI355X. N=4, D=256, H=W=64, fp32.
// Only 12 affinity offsets are ever used:
//   o0..o8  : 3x3 window (dy,dx in {-1,0,1})          -> mass
//   o0,o9..11: {(-1,-1),(-1,2),(2,-1),(2,2)}          -> agg weights
// Round-2 diagnosis: 256 blocks = 1/CU -> latency-bound (VALUBusy 8%,
// HBM 15%). Fix: split D across 4 blocks (1024-block reduce kernel),
// then tiny weights kernel, then 2048-block streaming apply kernel.

#define HH 64
#define WW 64
#define DD 256
#define HWD (HH * WW)
#define SPLITS 4
#define CPB (DD / SPLITS)   // 64 channels per partial-block
#define CPT (CPB / 8)       // 8 channels per thread

// d_ws float layout:
//   P[s][n][r][a][x] : 4*4*64*25*64 = 1,638,400 floats (6.55 MB)
//   W[n][j][r][x]    : 4*5*64*64    =    81,920 floats (0.33 MB)
#define P_IDX(s, n, r, a, x) (((((size_t)(s) * 4 + (n)) * 64 + (r)) * 25 + (a)) * 64 + (x))
#define W_OFF ((size_t)SPLITS * 4 * 64 * 25 * 64)
#define W_IDX(n, j, r, x) (W_OFF + ((((size_t)(n) * 5 + (j)) * 64 + (r)) * 64 + (x)))

__device__ __constant__ int c_ody[12] = {-1,-1,-1, 0,0,0, 1,1,1, -1, 2, 2};
__device__ __constant__ int c_odx[12] = {-1, 0, 1,-1,0,1,-1,0,1,  2,-1, 2};

// ---------------- K1: per-split partial reductions ----------------
__global__ __launch_bounds__(512, 8)
void fa_partial(const float* __restrict__ cur, const float* __restrict__ prev,
                float* __restrict__ ws)
{
    const int x  = threadIdx.x;   // 0..63 column
    const int tz = threadIdx.y;   // 0..7  channel group
    const int r  = blockIdx.x;    // row
    const int n  = blockIdx.y;    // batch
    const int s  = blockIdx.z;    // D split

    const size_t noff = (size_t)n * DD * HWD;
    const float* __restrict__ cur_n  = cur  + noff;
    const float* __restrict__ prev_n = prev + noff;

    int pidx[12];
    #pragma unroll
    for (int o = 0; o < 12; ++o) {
        int py = r + c_ody[o]; py = min(max(py, 0), HH - 1);
        int px = x + c_odx[o]; px = min(max(px, 0), WW - 1);
        pidx[o] = py * WW + px;
    }
    const int q = r * WW + x;

    // acc[0..11]=dot, acc[12..23]=pn^2, acc[24]=cn^2
    float acc[25];
    #pragma unroll
    for (int a = 0; a < 25; ++a) acc[a] = 0.f;

    const int d0 = s * CPB + tz * CPT;
    #pragma unroll
    for (int k = 0; k < CPT; ++k) {
        const int d = d0 + k;
        const float* __restrict__ cd = cur_n  + (size_t)d * HWD;
        const float* __restrict__ pd = prev_n + (size_t)d * HWD;
        const float c = cd[q];
        acc[24] = fmaf(c, c, acc[24]);
        #pragma unroll
        for (int o = 0; o < 12; ++o) {
            const float v = pd[pidx[o]];
            acc[o]      = fmaf(c, v, acc[o]);
            acc[12 + o] = fmaf(v, v, acc[12 + o]);
        }
    }

    // two-stage LDS reduce (13 then 12 accs) to keep LDS at 26.6 KB
    __shared__ float red[13][8][64];

    #pragma unroll
    for (int a = 0; a < 13; ++a) red[a][tz][x] = acc[a];
    __syncthreads();
    for (int a = tz; a < 13; a += 8) {
        float ssum = 0.f;
        #pragma unroll
        for (int z = 0; z < 8; ++z) ssum += red[a][z][x];
        ws[P_IDX(s, n, r, a, x)] = ssum;
    }
    __syncthreads();

    #pragma unroll
    for (int a = 13; a < 25; ++a) red[a - 13][tz][x] = acc[a];
    __syncthreads();
    for (int a = tz; a < 12; a += 8) {
        float ssum = 0.f;
        #pragma unroll
        for (int z = 0; z < 8; ++z) ssum += red[a][z][x];
        ws[P_IDX(s, n, r, a + 13, x)] = ssum;
    }
}

// ---------------- K2: reduce splits -> per-pixel weights ----------------
__global__ __launch_bounds__(256)
void fa_weights(float* __restrict__ ws)
{
    const int x = threadIdx.x;   // 0..63
    const int g = threadIdx.y;   // 0..3
    const int r = blockIdx.x;
    const int n = blockIdx.y;

    __shared__ float tot[25][64];
    for (int a = g; a < 25; a += 4) {
        float ssum = 0.f;
        #pragma unroll
        for (int s = 0; s < SPLITS; ++s) ssum += ws[P_IDX(s, n, r, a, x)];
        tot[a][x] = ssum;
    }
    __syncthreads();

    if (g == 0) {
        const float cn = sqrtf(tot[24][x]) + 1e-8f;
        float aff[12];
        #pragma unroll
        for (int o = 0; o < 12; ++o) {
            const float pn = sqrtf(tot[12 + o][x]) + 1e-8f;
            aff[o] = fmaxf(tot[o][x] / (cn * pn), 0.f);
        }
        float mass = 0.f;
        #pragma unroll
        for (int o = 0; o < 9; ++o) {
            const bool valid = (r + c_ody[o] >= 0) && (r + c_ody[o] < HH) &&
                               (x + c_odx[o] >= 0) && (x + c_odx[o] < WW);
            if (valid) mass += aff[o];
        }
        const bool  cond      = (mass > -10.f) && (mass < 10.f);
        const float mass_safe = (mass > 0.f) ? mass : 1.f;

        const int aggo[4] = {0, 9, 10, 11};
        #pragma unroll
        for (int j = 0; j < 4; ++j) {
            const int  o     = aggo[j];
            const bool valid = (r + c_ody[o] >= 0) && (r + c_ody[o] < HH) &&
                               (x + c_odx[o] >= 0) && (x + c_odx[o] < WW);
            const float a = aff[o];
            ws[W_IDX(n, j, r, x)] = (valid && a > 0.f) ? (a / mass_safe) : 0.f;
        }
        ws[W_IDX(n, 4, r, x)] = cond ? 1.f : 0.f;
    }
}

// ---------------- K3: streaming apply ----------------
__global__ __launch_bounds__(256)
void fa_apply(const float* __restrict__ mem, const float* __restrict__ ws,
              float* __restrict__ out)
{
    const int x = threadIdx.x;   // 0..63
    const int g = threadIdx.y;   // 0..3
    const int r = blockIdx.x;
    const int n = blockIdx.y;
    const int c = blockIdx.z;    // 0..7 : 32-channel chunk

    const size_t noff = (size_t)n * DD * HWD;
    const float* __restrict__ mem_n = mem + noff;
    float* __restrict__ out_n       = out + noff;

    const float w0 = ws[W_IDX(n, 0, r, x)];
    const float w1 = ws[W_IDX(n, 1, r, x)];
    const float w2 = ws[W_IDX(n, 2, r, x)];
    const float w3 = ws[W_IDX(n, 3, r, x)];
    const float cf = ws[W_IDX(n, 4, r, x)];

    const int ym = max(r - 1, 0), yp = min(r + 2, HH - 1);
    const int xm = max(x - 1, 0), xp = min(x + 2, WW - 1);
    const int p0 = ym * WW + xm;   // (-1,-1)
    const int p1 = ym * WW + xp;   // (-1,+2)
    const int p2 = yp * WW + xm;   // (+2,-1)
    const int p3 = yp * WW + xp;   // (+2,+2)
    const int q  = r * WW + x;

    const int d0 = c * 32 + g * 8;
    #pragma unroll
    for (int k = 0; k < 8; ++k) {
        const int d = d0 + k;
        const float* __restrict__ md = mem_n + (size_t)d * HWD;
        const float m   = md[q];
        const float agg = w0 * md[p0] + w1 * md[p1] + w2 * md[p2] + w3 * md[p3];
        const float res = m + ((d > 0) ? agg : 0.f);
        out_n[(size_t)d * HWD + q] = (cf != 0.f) ? res : 0.f;
    }
}

extern "C" void kernel_launch(void* const* d_in, const int* in_sizes, int n_in,
                              void* d_out, int out_size, void* d_ws, size_t ws_size,
                              hipStream_t stream)
{
    const float* cur  = (const float*)d_in[0];
    const float* prev = (const float*)d_in[1];
    const float* mem  = (const float*)d_in[2];
    float* out        = (float*)d_out;
    float* ws         = (float*)d_ws;

    {   // K1: 64 rows x 4 batch x 4 splits = 1024 blocks, 512 thr
        dim3 block(64, 8, 1), grid(HH, 4, SPLITS);
        hipLaunchKernelGGL(fa_partial, grid, block, 0, stream, cur, prev, ws);
    }
    {   // K2: 256 blocks, 256 thr (tiny)
        dim3 block(64, 4, 1), grid(HH, 4, 1);
        hipLaunchKernelGGL(fa_weights, grid, block, 0, stream, ws);
    }
    {   // K3: 2048 blocks, 256 thr, pure streaming
        dim3 block(64, 4, 1), grid(HH, 4, 8);
        hipLaunchKernelGGL(fa_apply, grid, block, 0, stream, mem, ws, out);
    }
}

// Round 4
// 110.367 us; speedup vs baseline: 1.2005x; 1.2005x over previous
//
#include <hip/hip_runtime.h>

// FeatureAlign, MI355X. N=4, D=256, H=W=64, fp32.
// Only 12 affinity offsets are ever used:
//   o0..o8  : 3x3 window (dy,dx in {-1,0,1})   -> mass
//   o0,o9..11: {(-1,-1),(-1,2),(2,-1),(2,2)}   -> agg weights
// Those offsets live on 4 rows (r-1,r,r+1,r+2) x col shifts {-1,0,1,2}.
// W = 64 = wave size: load each row ONCE per channel, produce shifted
// variants with 9 clamped __shfl (ds_bpermute) — 5 global loads/channel
// instead of 13, 14 accumulators instead of 25. pn^2 is per-pixel: K1
// accumulates it once (a=12); K2 gathers neighbor pn^2 from partials.

#define HH 64
#define WW 64
#define DD 256
#define HWD (HH * WW)
#define SPLITS 4
#define CPB (DD / SPLITS)   // 64 channels per split-block
#define CPT (CPB / 8)       // 8 channels per thread

#define NACC 14             // 0..11 dots, 12 pn^2(own), 13 cn^2(own)

// d_ws float layout:
//   P[s][n][r][a][x] : 4*4*64*14*64 = 917,504 floats (3.67 MB)
//   W[n][j][r][x]    : 4*5*64*64    =  81,920 floats (0.33 MB)
#define P_IDX(s, n, r, a, x) (((((size_t)(s) * 4 + (n)) * HH + (r)) * NACC + (a)) * WW + (x))
#define W_OFF ((size_t)SPLITS * 4 * HH * NACC * WW)
#define W_IDX(n, j, r, x) (W_OFF + ((((size_t)(n) * 5 + (j)) * HH + (r)) * WW + (x)))

__device__ __constant__ int c_ody[12] = {-1,-1,-1, 0,0,0, 1,1,1, -1, 2, 2};
__device__ __constant__ int c_odx[12] = {-1, 0, 1,-1,0,1,-1,0,1,  2,-1, 2};

// ---------------- K1: dot products via row-load + wave shuffles ----------------
__global__ __launch_bounds__(512)
void fa_dots(const float* __restrict__ cur, const float* __restrict__ prev,
             float* __restrict__ ws)
{
    const int x  = threadIdx.x;   // 0..63 column == lane
    const int tz = threadIdx.y;   // 0..7  channel group (one wave each)
    const int r  = blockIdx.x;
    const int n  = blockIdx.y;
    const int s  = blockIdx.z;

    const size_t noff = (size_t)n * DD * HWD;
    const float* __restrict__ cur_n  = cur  + noff;
    const float* __restrict__ prev_n = prev + noff;

    // clamped column-shift lanes (same for every channel)
    const int sm1 = max(x - 1, 0);
    const int sp1 = min(x + 1, WW - 1);
    const int sp2 = min(x + 2, WW - 1);

    // clamped row bases (element offsets within a channel plane)
    const int rA = max(r - 1, 0)      * WW + x;   // row r-1
    const int rB = r                  * WW + x;   // row r (own)
    const int rC = min(r + 1, HH - 1) * WW + x;   // row r+1
    const int rD = min(r + 2, HH - 1) * WW + x;   // row r+2

    float acc[NACC];
    #pragma unroll
    for (int a = 0; a < NACC; ++a) acc[a] = 0.f;

    const int d0 = s * CPB + tz * CPT;
    const float* __restrict__ cd = cur_n  + (size_t)d0 * HWD;
    const float* __restrict__ pd = prev_n + (size_t)d0 * HWD;

    #pragma unroll 2
    for (int k = 0; k < CPT; ++k) {
        const float c  = cd[rB];
        const float va = pd[rA];
        const float vb = pd[rB];
        const float vc = pd[rC];
        const float vd = pd[rD];
        cd += HWD;
        pd += HWD;

        const float vam = __shfl(va, sm1);
        const float vap = __shfl(va, sp1);
        const float va2 = __shfl(va, sp2);
        const float vbm = __shfl(vb, sm1);
        const float vbp = __shfl(vb, sp1);
        const float vcm = __shfl(vc, sm1);
        const float vcp = __shfl(vc, sp1);
        const float vdm = __shfl(vd, sm1);
        const float vd2 = __shfl(vd, sp2);

        acc[0]  = fmaf(c, vam, acc[0]);   // (-1,-1)
        acc[1]  = fmaf(c, va,  acc[1]);   // (-1, 0)
        acc[2]  = fmaf(c, vap, acc[2]);   // (-1,+1)
        acc[3]  = fmaf(c, vbm, acc[3]);   // ( 0,-1)
        acc[4]  = fmaf(c, vb,  acc[4]);   // ( 0, 0)
        acc[5]  = fmaf(c, vbp, acc[5]);   // ( 0,+1)
        acc[6]  = fmaf(c, vcm, acc[6]);   // (+1,-1)
        acc[7]  = fmaf(c, vc,  acc[7]);   // (+1, 0)
        acc[8]  = fmaf(c, vcp, acc[8]);   // (+1,+1)
        acc[9]  = fmaf(c, va2, acc[9]);   // (-1,+2)
        acc[10] = fmaf(c, vdm, acc[10]);  // (+2,-1)
        acc[11] = fmaf(c, vd2, acc[11]);  // (+2,+2)
        acc[12] = fmaf(vb, vb, acc[12]);  // pn^2 at own pixel
        acc[13] = fmaf(c,  c,  acc[13]);  // cn^2 at own pixel
    }

    __shared__ float red[NACC][8][WW];   // 28.7 KB
    #pragma unroll
    for (int a = 0; a < NACC; ++a) red[a][tz][x] = acc[a];
    __syncthreads();
    for (int a = tz; a < NACC; a += 8) {
        float t = 0.f;
        #pragma unroll
        for (int z = 0; z < 8; ++z) t += red[a][z][x];
        ws[P_IDX(s, n, r, a, x)] = t;
    }
}

// ---------------- K2: reduce splits, gather pn^2, compute weights ----------------
__global__ __launch_bounds__(256)
void fa_weights(float* __restrict__ ws)
{
    const int x = threadIdx.x;   // 0..63
    const int g = threadIdx.y;   // 0..3
    const int r = blockIdx.x;
    const int n = blockIdx.y;

    __shared__ float tot[NACC][WW];
    __shared__ float png[12][WW];    // gathered pn^2 per offset (split-summed)

    for (int a = g; a < NACC; a += 4) {
        float t = 0.f;
        #pragma unroll
        for (int s = 0; s < SPLITS; ++s) t += ws[P_IDX(s, n, r, a, x)];
        tot[a][x] = t;
    }
    for (int o = g; o < 12; o += 4) {
        const int rr = min(max(r + c_ody[o], 0), HH - 1);
        const int xx = min(max(x + c_odx[o], 0), WW - 1);
        float t = 0.f;
        #pragma unroll
        for (int s = 0; s < SPLITS; ++s) t += ws[P_IDX(s, n, rr, 12, xx)];
        png[o][x] = t;
    }
    __syncthreads();

    if (g == 0) {
        const float cn = sqrtf(tot[13][x]) + 1e-8f;
        float aff[12];
        #pragma unroll
        for (int o = 0; o < 12; ++o) {
            const float pn = sqrtf(png[o][x]) + 1e-8f;
            aff[o] = fmaxf(tot[o][x] / (cn * pn), 0.f);
        }
        float mass = 0.f;
        #pragma unroll
        for (int o = 0; o < 9; ++o) {
            const bool valid = (r + c_ody[o] >= 0) && (r + c_ody[o] < HH) &&
                               (x + c_odx[o] >= 0) && (x + c_odx[o] < WW);
            if (valid) mass += aff[o];
        }
        const bool  cond      = (mass > -10.f) && (mass < 10.f);
        const float mass_safe = (mass > 0.f) ? mass : 1.f;

        const int aggo[4] = {0, 9, 10, 11};
        #pragma unroll
        for (int j = 0; j < 4; ++j) {
            const int  o     = aggo[j];
            const bool valid = (r + c_ody[o] >= 0) && (r + c_ody[o] < HH) &&
                               (x + c_odx[o] >= 0) && (x + c_odx[o] < WW);
            const float a = aff[o];
            ws[W_IDX(n, j, r, x)] = (valid && a > 0.f) ? (a / mass_safe) : 0.f;
        }
        ws[W_IDX(n, 4, r, x)] = cond ? 1.f : 0.f;
    }
}

// ---------------- K3: streaming apply ----------------
__global__ __launch_bounds__(256)
void fa_apply(const float* __restrict__ mem, const float* __restrict__ ws,
              float* __restrict__ out)
{
    const int x = threadIdx.x;   // 0..63
    const int g = threadIdx.y;   // 0..3
    const int r = blockIdx.x;
    const int n = blockIdx.y;
    const int c = blockIdx.z;    // 0..7 : 32-channel chunk

    const size_t noff = (size_t)n * DD * HWD;
    const float* __restrict__ mem_n = mem + noff;
    float* __restrict__ out_n       = out + noff;

    const float w0 = ws[W_IDX(n, 0, r, x)];
    const float w1 = ws[W_IDX(n, 1, r, x)];
    const float w2 = ws[W_IDX(n, 2, r, x)];
    const float w3 = ws[W_IDX(n, 3, r, x)];
    const float cf = ws[W_IDX(n, 4, r, x)];

    const int ym = max(r - 1, 0), yp = min(r + 2, HH - 1);
    const int xm = max(x - 1, 0), xp = min(x + 2, WW - 1);
    const int p0 = ym * WW + xm;   // (-1,-1)
    const int p1 = ym * WW + xp;   // (-1,+2)
    const int p2 = yp * WW + xm;   // (+2,-1)
    const int p3 = yp * WW + xp;   // (+2,+2)
    const int q  = r * WW + x;

    const int d0 = c * 32 + g * 8;
    #pragma unroll
    for (int k = 0; k < 8; ++k) {
        const int d = d0 + k;
        const float* __restrict__ md = mem_n + (size_t)d * HWD;
        const float m   = md[q];
        const float agg = w0 * md[p0] + w1 * md[p1] + w2 * md[p2] + w3 * md[p3];
        const float res = m + ((d > 0) ? agg : 0.f);
        out_n[(size_t)d * HWD + q] = (cf != 0.f) ? res : 0.f;
    }
}

extern "C" void kernel_launch(void* const* d_in, const int* in_sizes, int n_in,
                              void* d_out, int out_size, void* d_ws, size_t ws_size,
                              hipStream_t stream)
{
    const float* cur  = (const float*)d_in[0];
    const float* prev = (const float*)d_in[1];
    const float* mem  = (const float*)d_in[2];
    float* out        = (float*)d_out;
    float* ws         = (float*)d_ws;

    {   // K1: 64 rows x 4 batch x 4 splits = 1024 blocks, 512 thr
        dim3 block(64, 8, 1), grid(HH, 4, SPLITS);
        hipLaunchKernelGGL(fa_dots, grid, block, 0, stream, cur, prev, ws);
    }
    {   // K2: 256 blocks, 256 thr
        dim3 block(64, 4, 1), grid(HH, 4, 1);
        hipLaunchKernelGGL(fa_weights, grid, block, 0, stream, ws);
    }
    {   // K3: 2048 blocks, 256 thr, pure streaming
        dim3 block(64, 4, 1), grid(HH, 4, 8);
        hipLaunchKernelGGL(fa_apply, grid, block, 0, stream, mem, ws, out);
    }
}

// Round 5
// 104.855 us; speedup vs baseline: 1.2636x; 1.0526x over previous
//
#include <hip/hip_runtime.h>

// FeatureAlign, MI355X. N=4, D=256, H=W=64, fp32.
// Only 12 affinity offsets are ever used:
//   o0..o8  : 3x3 window (dy,dx in {-1,0,1})   -> mass
//   o0,o9..11: {(-1,-1),(-1,2),(2,-1),(2,2)}   -> agg weights
// Offsets live on 4 rows (r-1,r,r+1,r+2) x col shifts {-1,0,1,2}:
// load each row once per channel, shift via 9 clamped __shfl.
// Round-4 diagnosis: reset floor ~63us; kernels ~47us. Fixes here:
//  (a) XCD-chunk swizzle (consecutive rows share an XCD's L2 so the
//      4x prev row overlap and K3 mem gathers hit L2, not HBM),
//  (b) K1 software pipeline: preload next channel's 5 rows (full unroll).

#define HH 64
#define WW 64
#define DD 256
#define HWD (HH * WW)
#define SPLITS 4
#define CPB (DD / SPLITS)   // 64 channels per split-block
#define CPT (CPB / 8)       // 8 channels per thread

#define NACC 14             // 0..11 dots, 12 pn^2(own), 13 cn^2(own)

// d_ws float layout:
//   P[s][n][r][a][x] : 4*4*64*14*64 = 917,504 floats (3.67 MB)
//   W[n][j][r][x]    : 4*5*64*64    =  81,920 floats (0.33 MB)
#define P_IDX(s, n, r, a, x) (((((size_t)(s) * 4 + (n)) * HH + (r)) * NACC + (a)) * WW + (x))
#define W_OFF ((size_t)SPLITS * 4 * HH * NACC * WW)
#define W_IDX(n, j, r, x) (W_OFF + ((((size_t)(n) * 5 + (j)) * HH + (r)) * WW + (x)))

__device__ __constant__ int c_ody[12] = {-1,-1,-1, 0,0,0, 1,1,1, -1, 2, 2};
__device__ __constant__ int c_odx[12] = {-1, 0, 1,-1,0,1,-1,0,1,  2,-1, 2};

// ---------------- K1: dots via row-load + wave shuffles, pipelined ----------------
__global__ __launch_bounds__(512)
void fa_dots(const float* __restrict__ cur, const float* __restrict__ prev,
             float* __restrict__ ws)
{
    // XCD-chunk swizzle: 1024 blocks = 8 XCDs x 128. XCD k gets logical
    // ids [128k,128k+128) = contiguous r (r fastest) -> neighbor-row prev
    // reads are XCD-L2-local.
    const int b = blockIdx.x;                 // 0..1023
    const int l = (b & 7) * 128 + (b >> 3);   // bijective
    const int r = l & 63;
    const int n = (l >> 6) & 3;
    const int s = l >> 8;                     // 0..3

    const int x  = threadIdx.x;   // 0..63 column == lane
    const int tz = threadIdx.y;   // 0..7  channel group (one wave each)

    const size_t noff = (size_t)n * DD * HWD;
    const float* __restrict__ cur_n  = cur  + noff;
    const float* __restrict__ prev_n = prev + noff;

    // clamped column-shift lanes (same for every channel)
    const int sm1 = max(x - 1, 0);
    const int sp1 = min(x + 1, WW - 1);
    const int sp2 = min(x + 2, WW - 1);

    // clamped row bases (element offsets within a channel plane)
    const int rA = max(r - 1, 0)      * WW + x;   // row r-1
    const int rB = r                  * WW + x;   // row r (own)
    const int rC = min(r + 1, HH - 1) * WW + x;   // row r+1
    const int rD = min(r + 2, HH - 1) * WW + x;   // row r+2

    float acc[NACC];
    #pragma unroll
    for (int a = 0; a < NACC; ++a) acc[a] = 0.f;

    const int d0 = s * CPB + tz * CPT;
    const float* __restrict__ cd = cur_n  + (size_t)d0 * HWD;
    const float* __restrict__ pd = prev_n + (size_t)d0 * HWD;

    // 1-deep software pipeline: loads for channel k+1 issue before the
    // shuffle/FMA chain of channel k retires.
    float c_ = cd[rB];
    float va = pd[rA];
    float vb = pd[rB];
    float vc = pd[rC];
    float vd = pd[rD];

    #pragma unroll
    for (int k = 0; k < CPT; ++k) {
        float cN = 0.f, aN = 0.f, bN = 0.f, cRN = 0.f, dN = 0.f;
        if (k + 1 < CPT) {
            const float* __restrict__ cd2 = cd + (size_t)(k + 1) * HWD;
            const float* __restrict__ pd2 = pd + (size_t)(k + 1) * HWD;
            cN  = cd2[rB];
            aN  = pd2[rA];
            bN  = pd2[rB];
            cRN = pd2[rC];
            dN  = pd2[rD];
        }

        const float vam = __shfl(va, sm1);
        const float vap = __shfl(va, sp1);
        const float va2 = __shfl(va, sp2);
        const float vbm = __shfl(vb, sm1);
        const float vbp = __shfl(vb, sp1);
        const float vcm = __shfl(vc, sm1);
        const float vcp = __shfl(vc, sp1);
        const float vdm = __shfl(vd, sm1);
        const float vd2 = __shfl(vd, sp2);

        acc[0]  = fmaf(c_, vam, acc[0]);   // (-1,-1)
        acc[1]  = fmaf(c_, va,  acc[1]);   // (-1, 0)
        acc[2]  = fmaf(c_, vap, acc[2]);   // (-1,+1)
        acc[3]  = fmaf(c_, vbm, acc[3]);   // ( 0,-1)
        acc[4]  = fmaf(c_, vb,  acc[4]);   // ( 0, 0)
        acc[5]  = fmaf(c_, vbp, acc[5]);   // ( 0,+1)
        acc[6]  = fmaf(c_, vcm, acc[6]);   // (+1,-1)
        acc[7]  = fmaf(c_, vc,  acc[7]);   // (+1, 0)
        acc[8]  = fmaf(c_, vcp, acc[8]);   // (+1,+1)
        acc[9]  = fmaf(c_, va2, acc[9]);   // (-1,+2)
        acc[10] = fmaf(c_, vdm, acc[10]);  // (+2,-1)
        acc[11] = fmaf(c_, vd2, acc[11]);  // (+2,+2)
        acc[12] = fmaf(vb, vb, acc[12]);   // pn^2 at own pixel
        acc[13] = fmaf(c_, c_, acc[13]);   // cn^2 at own pixel

        c_ = cN; va = aN; vb = bN; vc = cRN; vd = dN;
    }

    __shared__ float red[NACC][8][WW];   // 28.7 KB
    #pragma unroll
    for (int a = 0; a < NACC; ++a) red[a][tz][x] = acc[a];
    __syncthreads();
    for (int a = tz; a < NACC; a += 8) {
        float t = 0.f;
        #pragma unroll
        for (int z = 0; z < 8; ++z) t += red[a][z][x];
        ws[P_IDX(s, n, r, a, x)] = t;
    }
}

// ---------------- K2: reduce splits, gather pn^2, compute weights ----------------
__global__ __launch_bounds__(256)
void fa_weights(float* __restrict__ ws)
{
    const int x = threadIdx.x;   // 0..63
    const int g = threadIdx.y;   // 0..3
    const int r = blockIdx.x;
    const int n = blockIdx.y;

    __shared__ float tot[NACC][WW];
    __shared__ float png[12][WW];    // gathered pn^2 per offset (split-summed)

    for (int a = g; a < NACC; a += 4) {
        float t = 0.f;
        #pragma unroll
        for (int s = 0; s < SPLITS; ++s) t += ws[P_IDX(s, n, r, a, x)];
        tot[a][x] = t;
    }
    for (int o = g; o < 12; o += 4) {
        const int rr = min(max(r + c_ody[o], 0), HH - 1);
        const int xx = min(max(x + c_odx[o], 0), WW - 1);
        float t = 0.f;
        #pragma unroll
        for (int s = 0; s < SPLITS; ++s) t += ws[P_IDX(s, n, rr, 12, xx)];
        png[o][x] = t;
    }
    __syncthreads();

    if (g == 0) {
        const float cn = sqrtf(tot[13][x]) + 1e-8f;
        float aff[12];
        #pragma unroll
        for (int o = 0; o < 12; ++o) {
            const float pn = sqrtf(png[o][x]) + 1e-8f;
            aff[o] = fmaxf(tot[o][x] / (cn * pn), 0.f);
        }
        float mass = 0.f;
        #pragma unroll
        for (int o = 0; o < 9; ++o) {
            const bool valid = (r + c_ody[o] >= 0) && (r + c_ody[o] < HH) &&
                               (x + c_odx[o] >= 0) && (x + c_odx[o] < WW);
            if (valid) mass += aff[o];
        }
        const bool  cond      = (mass > -10.f) && (mass < 10.f);
        const float mass_safe = (mass > 0.f) ? mass : 1.f;

        const int aggo[4] = {0, 9, 10, 11};
        #pragma unroll
        for (int j = 0; j < 4; ++j) {
            const int  o     = aggo[j];
            const bool valid = (r + c_ody[o] >= 0) && (r + c_ody[o] < HH) &&
                               (x + c_odx[o] >= 0) && (x + c_odx[o] < WW);
            const float a = aff[o];
            ws[W_IDX(n, j, r, x)] = (valid && a > 0.f) ? (a / mass_safe) : 0.f;
        }
        ws[W_IDX(n, 4, r, x)] = cond ? 1.f : 0.f;
    }
}

// ---------------- K3: streaming apply ----------------
__global__ __launch_bounds__(256)
void fa_apply(const float* __restrict__ mem, const float* __restrict__ ws,
              float* __restrict__ out)
{
    // XCD-chunk swizzle: 2048 = 8 x 256. XCD k gets contiguous r for a
    // (n, c) slab -> the 5-row mem gathers stay XCD-L2-local.
    const int b = blockIdx.x;                 // 0..2047
    const int l = (b & 7) * 256 + (b >> 3);   // bijective
    const int r = l & 63;
    const int t = l >> 6;                     // 0..31
    const int n = t & 3;
    const int c = t >> 2;                     // 0..7

    const int x = threadIdx.x;   // 0..63
    const int g = threadIdx.y;   // 0..3

    const size_t noff = (size_t)n * DD * HWD;
    const float* __restrict__ mem_n = mem + noff;
    float* __restrict__ out_n       = out + noff;

    const float w0 = ws[W_IDX(n, 0, r, x)];
    const float w1 = ws[W_IDX(n, 1, r, x)];
    const float w2 = ws[W_IDX(n, 2, r, x)];
    const float w3 = ws[W_IDX(n, 3, r, x)];
    const float cf = ws[W_IDX(n, 4, r, x)];

    const int ym = max(r - 1, 0), yp = min(r + 2, HH - 1);
    const int xm = max(x - 1, 0), xp = min(x + 2, WW - 1);
    const int p0 = ym * WW + xm;   // (-1,-1)
    const int p1 = ym * WW + xp;   // (-1,+2)
    const int p2 = yp * WW + xm;   // (+2,-1)
    const int p3 = yp * WW + xp;   // (+2,+2)
    const int q  = r * WW + x;

    const int d0 = c * 32 + g * 8;
    #pragma unroll
    for (int k = 0; k < 8; ++k) {
        const int d = d0 + k;
        const float* __restrict__ md = mem_n + (size_t)d * HWD;
        const float m   = md[q];
        const float agg = w0 * md[p0] + w1 * md[p1] + w2 * md[p2] + w3 * md[p3];
        const float res = m + ((d > 0) ? agg : 0.f);
        out_n[(size_t)d * HWD + q] = (cf != 0.f) ? res : 0.f;
    }
}

extern "C" void kernel_launch(void* const* d_in, const int* in_sizes, int n_in,
                              void* d_out, int out_size, void* d_ws, size_t ws_size,
                              hipStream_t stream)
{
    const float* cur  = (const float*)d_in[0];
    const float* prev = (const float*)d_in[1];
    const float* mem  = (const float*)d_in[2];
    float* out        = (float*)d_out;
    float* ws         = (float*)d_ws;

    {   // K1: 1024 blocks (XCD-swizzled), 512 thr
        dim3 block(64, 8, 1), grid(1024, 1, 1);
        hipLaunchKernelGGL(fa_dots, grid, block, 0, stream, cur, prev, ws);
    }
    {   // K2: 256 blocks, 256 thr
        dim3 block(64, 4, 1), grid(HH, 4, 1);
        hipLaunchKernelGGL(fa_weights, grid, block, 0, stream, ws);
    }
    {   // K3: 2048 blocks (XCD-swizzled), 256 thr, streaming
        dim3 block(64, 4, 1), grid(2048, 1, 1);
        hipLaunchKernelGGL(fa_apply, grid, block, 0, stream, mem, ws, out);
    }
}